// Round 2
// baseline (862.054 us; speedup 1.0000x reference)
//
#include <hip/hip_runtime.h>
#include <hip/hip_bf16.h>

#define HID 256
#define HID2 512
#define NPG 200
#define LN_EPS 1e-5f

// ---------------------------------------------------------------------------
// K1: fused  x = h + g[batch];  z = x@W1 + b1;  LayerNorm; ReLU; logit = z.W2 + b2
// Block: 256 threads, 32 rows. Thread: rg=tid>>5 owns 4 rows, cg=tid&31 owns 16 cols.
// LN reduction over the 32 contiguous lanes sharing rg (xor 16..1 stays inside
// a 32-lane half of the wave64).
// ---------------------------------------------------------------------------
__global__ __launch_bounds__(256)
void mlp_logits_kernel(const float* __restrict__ h, const float* __restrict__ g,
                       const int* __restrict__ batch,
                       const float* __restrict__ W1, const float* __restrict__ b1,
                       const float* __restrict__ lng, const float* __restrict__ lnb,
                       const float* __restrict__ W2, const float* __restrict__ b2,
                       float* __restrict__ logits)
{
    __shared__ float xs[32][260];   // row stride 260 floats = 1040 B (16B aligned)
    const int tid  = threadIdx.x;
    const int row0 = blockIdx.x * 32;

    // ---- stage x tile: coalesced float4 loads, 4 rows per iteration ----
    {
        const int k4 = (tid & 63) << 2;   // 0..252
        const int rr = tid >> 6;          // 0..3
        #pragma unroll
        for (int i = 0; i < 8; ++i) {
            const int r    = (i << 2) + rr;
            const int grow = row0 + r;
            const int gb   = batch[grow];
            const float4 hv = *reinterpret_cast<const float4*>(h + (size_t)grow * HID + k4);
            const float4 gv = *reinterpret_cast<const float4*>(g + (size_t)gb   * HID + k4);
            float4 xv;
            xv.x = hv.x + gv.x; xv.y = hv.y + gv.y;
            xv.z = hv.z + gv.z; xv.w = hv.w + gv.w;
            *reinterpret_cast<float4*>(&xs[r][k4]) = xv;
        }
    }
    __syncthreads();

    const int rg = tid >> 5;        // 0..7  -> rows rg*4 .. rg*4+3
    const int cg = tid & 31;        // 0..31 -> cols cg*16 .. cg*16+15
    const int c0 = cg << 4;

    float acc[4][16];
    #pragma unroll
    for (int ri = 0; ri < 4; ++ri)
        #pragma unroll
        for (int ci = 0; ci < 16; ++ci) acc[ri][ci] = 0.0f;

    // ---- K loop ----
    for (int k0 = 0; k0 < HID; k0 += 4) {
        float4 xr[4];
        #pragma unroll
        for (int ri = 0; ri < 4; ++ri)
            xr[ri] = *reinterpret_cast<const float4*>(&xs[(rg << 2) + ri][k0]);
        #pragma unroll
        for (int kk = 0; kk < 4; ++kk) {
            const float* wrow = W1 + (size_t)(k0 + kk) * HID2 + c0;
            const float4 w0  = *reinterpret_cast<const float4*>(wrow);
            const float4 w1v = *reinterpret_cast<const float4*>(wrow + 4);
            const float4 w2v = *reinterpret_cast<const float4*>(wrow + 8);
            const float4 w3v = *reinterpret_cast<const float4*>(wrow + 12);
            const float w[16] = {w0.x,  w0.y,  w0.z,  w0.w,
                                 w1v.x, w1v.y, w1v.z, w1v.w,
                                 w2v.x, w2v.y, w2v.z, w2v.w,
                                 w3v.x, w3v.y, w3v.z, w3v.w};
            #pragma unroll
            for (int ri = 0; ri < 4; ++ri) {
                const float xv = reinterpret_cast<const float*>(&xr[ri])[kk];
                #pragma unroll
                for (int ci = 0; ci < 16; ++ci)
                    acc[ri][ci] = fmaf(xv, w[ci], acc[ri][ci]);
            }
        }
    }

    // ---- epilogue: +b1, LayerNorm (two-pass), ReLU, dot W2 ----
    float bv[16], gv2[16], bbv[16], wv2[16];
    #pragma unroll
    for (int j = 0; j < 4; ++j) {
        reinterpret_cast<float4*>(bv)[j]  = reinterpret_cast<const float4*>(b1  + c0)[j];
        reinterpret_cast<float4*>(gv2)[j] = reinterpret_cast<const float4*>(lng + c0)[j];
        reinterpret_cast<float4*>(bbv)[j] = reinterpret_cast<const float4*>(lnb + c0)[j];
        reinterpret_cast<float4*>(wv2)[j] = reinterpret_cast<const float4*>(W2  + c0)[j];
    }
    const float b2s = b2[0];

    #pragma unroll
    for (int ri = 0; ri < 4; ++ri) {
        #pragma unroll
        for (int ci = 0; ci < 16; ++ci) acc[ri][ci] += bv[ci];

        float s = 0.0f;
        #pragma unroll
        for (int ci = 0; ci < 16; ++ci) s += acc[ri][ci];
        s += __shfl_xor(s, 16); s += __shfl_xor(s, 8);
        s += __shfl_xor(s, 4);  s += __shfl_xor(s, 2); s += __shfl_xor(s, 1);
        const float mu = s * (1.0f / HID2);

        float q = 0.0f;
        #pragma unroll
        for (int ci = 0; ci < 16; ++ci) {
            const float d = acc[ri][ci] - mu;
            q = fmaf(d, d, q);
        }
        q += __shfl_xor(q, 16); q += __shfl_xor(q, 8);
        q += __shfl_xor(q, 4);  q += __shfl_xor(q, 2); q += __shfl_xor(q, 1);
        const float rstd = rsqrtf(q * (1.0f / HID2) + LN_EPS);

        float t = 0.0f;
        #pragma unroll
        for (int ci = 0; ci < 16; ++ci) {
            float zn = (acc[ri][ci] - mu) * rstd * gv2[ci] + bbv[ci];
            zn = fmaxf(zn, 0.0f);
            t = fmaf(zn, wv2[ci], t);
        }
        t += __shfl_xor(t, 16); t += __shfl_xor(t, 8);
        t += __shfl_xor(t, 4);  t += __shfl_xor(t, 2); t += __shfl_xor(t, 1);

        if (cg == 0) logits[row0 + (rg << 2) + ri] = t + b2s;
    }
}

// ---------------------------------------------------------------------------
// K2: per-graph softmax + seed selection (first-index max of node_prob).
// One block of 256 threads per graph (200 active).
// ---------------------------------------------------------------------------
__global__ __launch_bounds__(256)
void softmax_seed_kernel(const float* __restrict__ logits,
                         float* __restrict__ out_prob,
                         unsigned char* __restrict__ nm)
{
    const int gid  = blockIdx.x;
    const int tid  = threadIdx.x;
    const int node = gid * NPG + tid;
    const bool act = tid < NPG;

    __shared__ float redf[4];
    __shared__ int   redi[4];

    float l = act ? logits[node] : -INFINITY;

    float m = l;
    #pragma unroll
    for (int off = 32; off >= 1; off >>= 1) m = fmaxf(m, __shfl_xor(m, off));
    if ((tid & 63) == 0) redf[tid >> 6] = m;
    __syncthreads();
    const float bm = fmaxf(fmaxf(redf[0], redf[1]), fmaxf(redf[2], redf[3]));
    __syncthreads();

    const float e = act ? expf(l - bm) : 0.0f;
    float s = e;
    #pragma unroll
    for (int off = 32; off >= 1; off >>= 1) s += __shfl_xor(s, off);
    if ((tid & 63) == 0) redf[tid >> 6] = s;
    __syncthreads();
    const float bs = redf[0] + redf[1] + redf[2] + redf[3];
    __syncthreads();

    const float p = act ? e / bs : -1.0f;
    if (act) out_prob[node] = p;

    float pm = p;
    #pragma unroll
    for (int off = 32; off >= 1; off >>= 1) pm = fmaxf(pm, __shfl_xor(pm, off));
    if ((tid & 63) == 0) redf[tid >> 6] = pm;
    __syncthreads();
    const float bpm = fmaxf(fmaxf(redf[0], redf[1]), fmaxf(redf[2], redf[3]));

    int c = (act && p >= bpm) ? node : 0x7FFFFFFF;
    #pragma unroll
    for (int off = 32; off >= 1; off >>= 1) c = min(c, __shfl_xor(c, off));
    if ((tid & 63) == 0) redi[tid >> 6] = c;
    __syncthreads();
    if (tid == 0) {
        const int seed = min(min(redi[0], redi[1]), min(redi[2], redi[3]));
        nm[seed] = 1;   // mark seed at level 1
    }
}

// ---------------------------------------------------------------------------
// K3/K4: one synchronous BFS hop (expand target -> source).
// Level tags prevent intra-pass propagation: pass P expands only levels<=P.
// Races benign (same-value byte stores; level-(P+1) nodes never expand in pass P).
// ---------------------------------------------------------------------------
__global__ __launch_bounds__(256)
void bfs_pass_kernel(const int* __restrict__ ei, unsigned char* __restrict__ nm,
                     const int E, const int maxlvl, const int newlvl)
{
    const int stride = gridDim.x * blockDim.x;
    for (int e = blockIdx.x * blockDim.x + threadIdx.x; e < E; e += stride) {
        const int d  = ei[E + e];
        const int lv = nm[d];
        if (lv >= 1 && lv <= maxlvl) {
            const int s = ei[e];
            if (nm[s] == 0) nm[s] = (unsigned char)newlvl;
        }
    }
}

// ---------------------------------------------------------------------------
// K5: edge outputs + node-mask scatter (float32 outputs)
// ---------------------------------------------------------------------------
__global__ __launch_bounds__(256)
void edge_out_kernel(const int* __restrict__ ei, const float* __restrict__ logits,
                     const unsigned char* __restrict__ nm,
                     float* __restrict__ out_ew,
                     float* __restrict__ out_em,
                     unsigned char* __restrict__ nodemask, const int E)
{
    const int stride = gridDim.x * blockDim.x;
    for (int e = blockIdx.x * blockDim.x + threadIdx.x; e < E; e += stride) {
        const int s = ei[e];
        const int d = ei[E + e];
        const float lw = logits[s] + logits[d];
        const bool em  = (nm[s] != 0) && (nm[d] != 0);
        out_ew[e] = lw;
        out_em[e] = em ? 1.0f : 0.0f;
        if (em) { nodemask[s] = 1; nodemask[d] = 1; }
    }
}

// ---------------------------------------------------------------------------
// K6: node_mask -> float32 output
// ---------------------------------------------------------------------------
__global__ __launch_bounds__(256)
void node_mask_kernel(const unsigned char* __restrict__ nodemask,
                      float* __restrict__ out_nm, const int N)
{
    const int stride = gridDim.x * blockDim.x;
    for (int i = blockIdx.x * blockDim.x + threadIdx.x; i < N; i += stride)
        out_nm[i] = nodemask[i] ? 1.0f : 0.0f;
}

// ---------------------------------------------------------------------------
// K0: zero the nm + nodemask scratch
// ---------------------------------------------------------------------------
__global__ __launch_bounds__(256)
void zero_ws_kernel(uint4* __restrict__ p, const int n16)
{
    const int i = blockIdx.x * blockDim.x + threadIdx.x;
    if (i < n16) p[i] = make_uint4(0u, 0u, 0u, 0u);
}

extern "C" void kernel_launch(void* const* d_in, const int* in_sizes, int n_in,
                              void* d_out, int out_size, void* d_ws, size_t ws_size,
                              hipStream_t stream)
{
    const float* h     = (const float*)d_in[0];
    const float* g     = (const float*)d_in[1];
    const int*   batch = (const int*)d_in[2];
    const int*   ei    = (const int*)d_in[3];
    const float* W1    = (const float*)d_in[4];
    const float* b1    = (const float*)d_in[5];
    const float* lng   = (const float*)d_in[6];
    const float* lnb   = (const float*)d_in[7];
    const float* W2    = (const float*)d_in[8];
    const float* b2    = (const float*)d_in[9];

    const int N = in_sizes[2];
    const int E = in_sizes[3] / 2;

    float* out        = (float*)d_out;
    float* out_prob   = out;                                  // [N]
    float* out_ew     = out + N;                              // [E]
    float* out_em     = out + (size_t)N + E;                  // [E]
    float* out_nmask  = out + (size_t)N + 2 * (size_t)E;      // [N]

    float*         logits   = (float*)d_ws;
    unsigned char* nm       = (unsigned char*)d_ws + (size_t)N * 4;
    unsigned char* nodemask = nm + N;

    // zero nm + nodemask (2N bytes, 16B-aligned region right after logits)
    const int n16 = (2 * N) / 16;
    zero_ws_kernel<<<(n16 + 255) / 256, 256, 0, stream>>>((uint4*)nm, n16);

    mlp_logits_kernel<<<N / 32, 256, 0, stream>>>(h, g, batch, W1, b1, lng, lnb,
                                                  W2, b2, logits);
    softmax_seed_kernel<<<N / NPG, 256, 0, stream>>>(logits, out_prob, nm);
    bfs_pass_kernel<<<4096, 256, 0, stream>>>(ei, nm, E, 1, 2);
    bfs_pass_kernel<<<4096, 256, 0, stream>>>(ei, nm, E, 2, 3);
    edge_out_kernel<<<4096, 256, 0, stream>>>(ei, logits, nm, out_ew, out_em,
                                              nodemask, E);
    node_mask_kernel<<<512, 256, 0, stream>>>(nodemask, out_nmask, N);
}

// Round 3
// 581.079 us; speedup vs baseline: 1.4835x; 1.4835x over previous
//
#include <hip/hip_runtime.h>
#include <hip/hip_bf16.h>

#define HID 256
#define HID2 512
#define NPG 200
#define LN_EPS 1e-5f

typedef float f32x4 __attribute__((ext_vector_type(4)));
typedef short s16x8 __attribute__((ext_vector_type(8)));
typedef unsigned short ushort_t;

// round-to-nearest-even float -> bf16 bit pattern
__device__ __forceinline__ ushort_t f2bf_rne(float x) {
    union { float f; unsigned int u; } c; c.f = x;
    unsigned int u = c.u;
    return (ushort_t)((u + 0x7fffu + ((u >> 16) & 1u)) >> 16);
}
__device__ __forceinline__ float bf2f(ushort_t h) {
    union { unsigned int u; float f; } c; c.u = ((unsigned int)h) << 16;
    return c.f;
}

// ---------------------------------------------------------------------------
// K_w1: transpose + bf16-split W1[256][512] -> W1T_hi/lo[512][256] (K-contiguous)
// ---------------------------------------------------------------------------
__global__ __launch_bounds__(256)
void w1_prep_kernel(const float* __restrict__ W1,
                    ushort_t* __restrict__ w1h, ushort_t* __restrict__ w1l)
{
    const int c = blockIdx.x;      // W1 column = W1T row, 0..511
    const int k = threadIdx.x;     // 0..255
    const float v = W1[(size_t)k * HID2 + c];
    const ushort_t hi = f2bf_rne(v);
    const float resid = v - bf2f(hi);
    const ushort_t lo = f2bf_rne(resid);
    w1h[(size_t)c * HID + k] = hi;
    w1l[(size_t)c * HID + k] = lo;
}

// ---------------------------------------------------------------------------
// K1: fused  x = h + g[batch];  z = x@W1 + b1;  LayerNorm; ReLU; logit = z.W2+b2
// MFMA bf16 2x2-split (4 mfma_f32_16x16x32_bf16 per K-chunk per tile).
// Block: 256 threads = 4 waves, BM=64 rows. Wave w owns rows w*16..w*16+15,
// all 512 cols (32 col-tiles, f32x4 acc each).
// ---------------------------------------------------------------------------
__global__ __launch_bounds__(256)
void mlp_logits_mfma(const float* __restrict__ h, const float* __restrict__ g,
                     const int* __restrict__ batch,
                     const ushort_t* __restrict__ w1h, const ushort_t* __restrict__ w1l,
                     const float* __restrict__ b1,
                     const float* __restrict__ lng, const float* __restrict__ lnb,
                     const float* __restrict__ W2, const float* __restrict__ b2,
                     float* __restrict__ logits)
{
    __shared__ ushort_t xsh[64 * 256];   // 32 KB, swizzled
    __shared__ ushort_t xsl[64 * 256];   // 32 KB, swizzled
    __shared__ float prm[4 * 512];       // b1 | lng | lnb | W2

    const int tid  = threadIdx.x;
    const int row0 = blockIdx.x * 64;

    // ---- params -> LDS ----
    #pragma unroll
    for (int i = 0; i < 2; ++i) {
        const int c = tid + i * 256;
        prm[c]        = b1[c];
        prm[512 + c]  = lng[c];
        prm[1024 + c] = lnb[c];
        prm[1536 + c] = W2[c];
    }

    // ---- stage x = h + g[batch], split to bf16 hi/lo in swizzled LDS ----
    #pragma unroll
    for (int i = 0; i < 8; ++i) {
        const int ci = tid + (i << 8);      // 0..2047
        const int r  = ci >> 5;             // 0..63
        const int kc = (ci & 31) << 3;      // 0..248
        const int grow = row0 + r;
        const int gb   = batch[grow];
        const float4* hp = reinterpret_cast<const float4*>(h + (size_t)grow * HID + kc);
        const float4* gp = reinterpret_cast<const float4*>(g + (size_t)gb   * HID + kc);
        const float4 h0 = hp[0], h1 = hp[1];
        const float4 g0 = gp[0], g1 = gp[1];
        float xv[8] = { h0.x + g0.x, h0.y + g0.y, h0.z + g0.z, h0.w + g0.w,
                        h1.x + g1.x, h1.y + g1.y, h1.z + g1.z, h1.w + g1.w };
        ushort_t hh[8], ll[8];
        #pragma unroll
        for (int j = 0; j < 8; ++j) {
            const ushort_t hi = f2bf_rne(xv[j]);
            hh[j] = hi;
            ll[j] = f2bf_rne(xv[j] - bf2f(hi));
        }
        int byte_off = r * 512 + (kc << 1);
        byte_off ^= (r & 7) << 4;
        *reinterpret_cast<s16x8*>(reinterpret_cast<char*>(xsh) + byte_off) =
            *reinterpret_cast<const s16x8*>(hh);
        *reinterpret_cast<s16x8*>(reinterpret_cast<char*>(xsl) + byte_off) =
            *reinterpret_cast<const s16x8*>(ll);
    }
    __syncthreads();

    const int w  = tid >> 6;       // wave 0..3 -> rows w*16..+15
    const int l  = tid & 63;
    const int lc = l & 15;         // col-in-tile / row-in-tile index
    const int kg = l >> 4;         // k-chunk group 0..3

    f32x4 acc[32];
    #pragma unroll
    for (int ct = 0; ct < 32; ++ct) acc[ct] = (f32x4){0.f, 0.f, 0.f, 0.f};

    const int arow = (w << 4) | lc;
    for (int k0 = 0; k0 < HID; k0 += 32) {
        const int koff = k0 + (kg << 3);
        int abyte = arow * 512 + (koff << 1);
        abyte ^= (arow & 7) << 4;
        const s16x8 ah = *reinterpret_cast<const s16x8*>(
                             reinterpret_cast<const char*>(xsh) + abyte);
        const s16x8 al = *reinterpret_cast<const s16x8*>(
                             reinterpret_cast<const char*>(xsl) + abyte);
        #pragma unroll
        for (int ct = 0; ct < 32; ++ct) {
            const size_t boff = (size_t)(ct * 16 + lc) * HID + koff;
            const s16x8 bh = *reinterpret_cast<const s16x8*>(w1h + boff);
            const s16x8 bl = *reinterpret_cast<const s16x8*>(w1l + boff);
            acc[ct] = __builtin_amdgcn_mfma_f32_16x16x32_bf16(ah, bh, acc[ct], 0, 0, 0);
            acc[ct] = __builtin_amdgcn_mfma_f32_16x16x32_bf16(al, bh, acc[ct], 0, 0, 0);
            acc[ct] = __builtin_amdgcn_mfma_f32_16x16x32_bf16(ah, bl, acc[ct], 0, 0, 0);
            acc[ct] = __builtin_amdgcn_mfma_f32_16x16x32_bf16(al, bl, acc[ct], 0, 0, 0);
        }
    }

    // ---- epilogue: +b1, LayerNorm, ReLU, dot W2 ----
    // C-layout: lane holds col c = ct*16+lc, rows (kg*4 + reg), reg=0..3.
    #pragma unroll
    for (int ct = 0; ct < 32; ++ct) {
        const float bb = prm[ct * 16 + lc];
        acc[ct][0] += bb; acc[ct][1] += bb; acc[ct][2] += bb; acc[ct][3] += bb;
    }

    const float b2s = b2[0];
    float tt[4];
    #pragma unroll
    for (int reg = 0; reg < 4; ++reg) {
        float s = 0.f;
        #pragma unroll
        for (int ct = 0; ct < 32; ++ct) s += acc[ct][reg];
        s += __shfl_xor(s, 1); s += __shfl_xor(s, 2);
        s += __shfl_xor(s, 4); s += __shfl_xor(s, 8);
        const float mu = s * (1.0f / HID2);

        float q = 0.f;
        #pragma unroll
        for (int ct = 0; ct < 32; ++ct) {
            const float d = acc[ct][reg] - mu;
            q = fmaf(d, d, q);
        }
        q += __shfl_xor(q, 1); q += __shfl_xor(q, 2);
        q += __shfl_xor(q, 4); q += __shfl_xor(q, 8);
        const float rstd = rsqrtf(q * (1.0f / HID2) + LN_EPS);

        float t = 0.f;
        #pragma unroll
        for (int ct = 0; ct < 32; ++ct) {
            const int c = ct * 16 + lc;
            float zn = (acc[ct][reg] - mu) * rstd * prm[512 + c] + prm[1024 + c];
            zn = fmaxf(zn, 0.f);
            t = fmaf(zn, prm[1536 + c], t);
        }
        t += __shfl_xor(t, 1); t += __shfl_xor(t, 2);
        t += __shfl_xor(t, 4); t += __shfl_xor(t, 8);
        tt[reg] = t + b2s;
    }
    if (lc == 0) {
        #pragma unroll
        for (int reg = 0; reg < 4; ++reg)
            logits[row0 + (w << 4) + (kg << 2) + reg] = tt[reg];
    }
}

// ---------------------------------------------------------------------------
// K2: per-graph softmax + seed selection (first-index max of node_prob).
// ---------------------------------------------------------------------------
__global__ __launch_bounds__(256)
void softmax_seed_kernel(const float* __restrict__ logits,
                         float* __restrict__ out_prob,
                         unsigned char* __restrict__ nm)
{
    const int gid  = blockIdx.x;
    const int tid  = threadIdx.x;
    const int node = gid * NPG + tid;
    const bool act = tid < NPG;

    __shared__ float redf[4];
    __shared__ int   redi[4];

    float l = act ? logits[node] : -INFINITY;

    float m = l;
    #pragma unroll
    for (int off = 32; off >= 1; off >>= 1) m = fmaxf(m, __shfl_xor(m, off));
    if ((tid & 63) == 0) redf[tid >> 6] = m;
    __syncthreads();
    const float bm = fmaxf(fmaxf(redf[0], redf[1]), fmaxf(redf[2], redf[3]));
    __syncthreads();

    const float e = act ? expf(l - bm) : 0.0f;
    float s = e;
    #pragma unroll
    for (int off = 32; off >= 1; off >>= 1) s += __shfl_xor(s, off);
    if ((tid & 63) == 0) redf[tid >> 6] = s;
    __syncthreads();
    const float bs = redf[0] + redf[1] + redf[2] + redf[3];
    __syncthreads();

    const float p = act ? e / bs : -1.0f;
    if (act) out_prob[node] = p;

    float pm = p;
    #pragma unroll
    for (int off = 32; off >= 1; off >>= 1) pm = fmaxf(pm, __shfl_xor(pm, off));
    if ((tid & 63) == 0) redf[tid >> 6] = pm;
    __syncthreads();
    const float bpm = fmaxf(fmaxf(redf[0], redf[1]), fmaxf(redf[2], redf[3]));

    int c = (act && p >= bpm) ? node : 0x7FFFFFFF;
    #pragma unroll
    for (int off = 32; off >= 1; off >>= 1) c = min(c, __shfl_xor(c, off));
    if ((tid & 63) == 0) redi[tid >> 6] = c;
    __syncthreads();
    if (tid == 0) {
        const int seed = min(min(redi[0], redi[1]), min(redi[2], redi[3]));
        nm[seed] = 1;   // level 1
    }
}

// ---------------------------------------------------------------------------
// K3/K4: one synchronous BFS hop (expand target -> source), level-tagged.
// ---------------------------------------------------------------------------
__global__ __launch_bounds__(256)
void bfs_pass_kernel(const int* __restrict__ ei, unsigned char* __restrict__ nm,
                     const int E, const int maxlvl, const int newlvl)
{
    const int stride = gridDim.x * blockDim.x;
    for (int e = blockIdx.x * blockDim.x + threadIdx.x; e < E; e += stride) {
        const int d  = ei[E + e];
        const int lv = nm[d];
        if (lv >= 1 && lv <= maxlvl) {
            const int s = ei[e];
            if (nm[s] == 0) nm[s] = (unsigned char)newlvl;
        }
    }
}

// ---------------------------------------------------------------------------
// K5: edge outputs + node-mask scatter (float32 outputs)
// ---------------------------------------------------------------------------
__global__ __launch_bounds__(256)
void edge_out_kernel(const int* __restrict__ ei, const float* __restrict__ logits,
                     const unsigned char* __restrict__ nm,
                     float* __restrict__ out_ew,
                     float* __restrict__ out_em,
                     unsigned char* __restrict__ nodemask, const int E)
{
    const int stride = gridDim.x * blockDim.x;
    for (int e = blockIdx.x * blockDim.x + threadIdx.x; e < E; e += stride) {
        const int s = ei[e];
        const int d = ei[E + e];
        const float lw = logits[s] + logits[d];
        const bool em  = (nm[s] != 0) && (nm[d] != 0);
        out_ew[e] = lw;
        out_em[e] = em ? 1.0f : 0.0f;
        if (em) { nodemask[s] = 1; nodemask[d] = 1; }
    }
}

// ---------------------------------------------------------------------------
// K6: node_mask -> float32 output
// ---------------------------------------------------------------------------
__global__ __launch_bounds__(256)
void node_mask_kernel(const unsigned char* __restrict__ nodemask,
                      float* __restrict__ out_nm, const int N)
{
    const int stride = gridDim.x * blockDim.x;
    for (int i = blockIdx.x * blockDim.x + threadIdx.x; i < N; i += stride)
        out_nm[i] = nodemask[i] ? 1.0f : 0.0f;
}

// ---------------------------------------------------------------------------
// K0: zero nm + nodemask scratch
// ---------------------------------------------------------------------------
__global__ __launch_bounds__(256)
void zero_ws_kernel(uint4* __restrict__ p, const int n16)
{
    const int i = blockIdx.x * blockDim.x + threadIdx.x;
    if (i < n16) p[i] = make_uint4(0u, 0u, 0u, 0u);
}

extern "C" void kernel_launch(void* const* d_in, const int* in_sizes, int n_in,
                              void* d_out, int out_size, void* d_ws, size_t ws_size,
                              hipStream_t stream)
{
    const float* h     = (const float*)d_in[0];
    const float* g     = (const float*)d_in[1];
    const int*   batch = (const int*)d_in[2];
    const int*   ei    = (const int*)d_in[3];
    const float* W1    = (const float*)d_in[4];
    const float* b1    = (const float*)d_in[5];
    const float* lng   = (const float*)d_in[6];
    const float* lnb   = (const float*)d_in[7];
    const float* W2    = (const float*)d_in[8];
    const float* b2    = (const float*)d_in[9];

    const int N = in_sizes[2];
    const int E = in_sizes[3] / 2;

    float* out        = (float*)d_out;
    float* out_prob   = out;                                  // [N]
    float* out_ew     = out + N;                              // [E]
    float* out_em     = out + (size_t)N + E;                  // [E]
    float* out_nmask  = out + (size_t)N + 2 * (size_t)E;      // [N]

    // workspace layout
    char* ws = (char*)d_ws;
    float*         logits   = (float*)ws;                               // N*4
    ushort_t*      w1h      = (ushort_t*)(ws + (size_t)N * 4);          // 512*256*2
    ushort_t*      w1l      = (ushort_t*)(ws + (size_t)N * 4 + 262144);
    unsigned char* nm       = (unsigned char*)(ws + (size_t)N * 4 + 524288);
    unsigned char* nodemask = nm + N;

    // zero nm + nodemask (2N bytes, 16B aligned)
    const int n16 = (2 * N) / 16;
    zero_ws_kernel<<<(n16 + 255) / 256, 256, 0, stream>>>((uint4*)nm, n16);

    w1_prep_kernel<<<HID2, HID, 0, stream>>>(W1, w1h, w1l);

    mlp_logits_mfma<<<N / 64, 256, 0, stream>>>(h, g, batch, w1h, w1l,
                                                b1, lng, lnb, W2, b2, logits);
    softmax_seed_kernel<<<N / NPG, 256, 0, stream>>>(logits, out_prob, nm);
    bfs_pass_kernel<<<4096, 256, 0, stream>>>(ei, nm, E, 1, 2);
    bfs_pass_kernel<<<4096, 256, 0, stream>>>(ei, nm, E, 2, 3);
    edge_out_kernel<<<4096, 256, 0, stream>>>(ei, logits, nm, out_ew, out_em,
                                              nodemask, E);
    node_mask_kernel<<<512, 256, 0, stream>>>(nodemask, out_nmask, N);
}

// Round 4
// 331.727 us; speedup vs baseline: 2.5987x; 1.7517x over previous
//
#include <hip/hip_runtime.h>
#include <hip/hip_bf16.h>

#define HID 256
#define HID2 512
#define NPG 200
#define LN_EPS 1e-5f

typedef float f32x4 __attribute__((ext_vector_type(4)));
typedef short s16x8 __attribute__((ext_vector_type(8)));
typedef unsigned short ushort_t;

// round-to-nearest-even float -> bf16 bit pattern
__device__ __forceinline__ ushort_t f2bf_rne(float x) {
    union { float f; unsigned int u; } c; c.f = x;
    unsigned int u = c.u;
    return (ushort_t)((u + 0x7fffu + ((u >> 16) & 1u)) >> 16);
}
__device__ __forceinline__ float bf2f(ushort_t h) {
    union { unsigned int u; float f; } c; c.u = ((unsigned int)h) << 16;
    return c.f;
}

// ---------------------------------------------------------------------------
// K_w1: transpose + bf16-split W1[256][512] -> W1T_hi/lo[512][256] (K-contiguous)
// ---------------------------------------------------------------------------
__global__ __launch_bounds__(256)
void w1_prep_kernel(const float* __restrict__ W1,
                    ushort_t* __restrict__ w1h, ushort_t* __restrict__ w1l)
{
    const int c = blockIdx.x;      // W1 column = W1T row, 0..511
    const int k = threadIdx.x;     // 0..255
    const float v = W1[(size_t)k * HID2 + c];
    const ushort_t hi = f2bf_rne(v);
    const float resid = v - bf2f(hi);
    const ushort_t lo = f2bf_rne(resid);
    w1h[(size_t)c * HID + k] = hi;
    w1l[(size_t)c * HID + k] = lo;
}

// ---------------------------------------------------------------------------
// K1: fused  x = h + g[batch];  z = x@W1 + b1;  LayerNorm; ReLU; logit = z.W2+b2
// bf16x3 MFMA. Block: 256 thr = 4 waves, BM=64 rows.
// Wave w owns cols w*128..+127 (8 col-tiles) x all 64 rows (4 row-tiles).
// B-frags from global (L1/L2-resident, loop-invariant lane base), A from
// swizzled LDS. Cross-wave LN/W2 reduction via LDS.
// ---------------------------------------------------------------------------
__global__ __launch_bounds__(256)
void mlp_logits_mfma(const float* __restrict__ h, const float* __restrict__ g,
                     const int* __restrict__ batch,
                     const ushort_t* __restrict__ w1h, const ushort_t* __restrict__ w1l,
                     const float* __restrict__ b1,
                     const float* __restrict__ lng, const float* __restrict__ lnb,
                     const float* __restrict__ W2, const float* __restrict__ b2,
                     float* __restrict__ logits)
{
    __shared__ ushort_t xsh[64 * 256];   // 32 KB, swizzled
    __shared__ ushort_t xsl[64 * 256];   // 32 KB, swizzled
    __shared__ float prm[4 * 512];       // b1 | lng | lnb | W2
    __shared__ float redS1[4][64];
    __shared__ float redS2[4][64];
    __shared__ float redT[4][64];
    __shared__ float muv[64], rsv[64];

    const int tid  = threadIdx.x;
    const int row0 = blockIdx.x * 64;

    // ---- params -> LDS ----
    #pragma unroll
    for (int i = 0; i < 2; ++i) {
        const int c = tid + i * 256;
        prm[c]        = b1[c];
        prm[512 + c]  = lng[c];
        prm[1024 + c] = lnb[c];
        prm[1536 + c] = W2[c];
    }

    // ---- stage x = h + g[batch], split to bf16 hi/lo in swizzled LDS ----
    #pragma unroll
    for (int i = 0; i < 8; ++i) {
        const int ci = tid + (i << 8);      // 0..2047
        const int r  = ci >> 5;             // 0..63
        const int kc = (ci & 31) << 3;      // 0..248
        const int grow = row0 + r;
        const int gb   = batch[grow];
        const float4* hp = reinterpret_cast<const float4*>(h + (size_t)grow * HID + kc);
        const float4* gp = reinterpret_cast<const float4*>(g + (size_t)gb   * HID + kc);
        const float4 h0 = hp[0], h1 = hp[1];
        const float4 g0 = gp[0], g1 = gp[1];
        float xv[8] = { h0.x + g0.x, h0.y + g0.y, h0.z + g0.z, h0.w + g0.w,
                        h1.x + g1.x, h1.y + g1.y, h1.z + g1.z, h1.w + g1.w };
        ushort_t hh[8], ll[8];
        #pragma unroll
        for (int j = 0; j < 8; ++j) {
            const ushort_t hi = f2bf_rne(xv[j]);
            hh[j] = hi;
            ll[j] = f2bf_rne(xv[j] - bf2f(hi));
        }
        int byte_off = r * 512 + (kc << 1);
        byte_off ^= (r & 7) << 4;
        *reinterpret_cast<s16x8*>(reinterpret_cast<char*>(xsh) + byte_off) =
            *reinterpret_cast<const s16x8*>(hh);
        *reinterpret_cast<s16x8*>(reinterpret_cast<char*>(xsl) + byte_off) =
            *reinterpret_cast<const s16x8*>(ll);
    }
    __syncthreads();

    const int w  = tid >> 6;       // wave 0..3 -> cols w*128..+127
    const int l  = tid & 63;
    const int lc = l & 15;         // A-row / B-col / C-col index within tile
    const int gq = l >> 4;         // k-chunk group 0..3 (and C row group)
    const int wcol0 = w << 7;

    f32x4 acc[4][8];
    #pragma unroll
    for (int rt = 0; rt < 4; ++rt)
        #pragma unroll
        for (int ct = 0; ct < 8; ++ct) acc[rt][ct] = (f32x4){0.f, 0.f, 0.f, 0.f};

    // loop-invariant B lane base: col = wcol0 + ct*16 + lc, k base = gq*8
    const size_t bbase = (size_t)(wcol0 + lc) * HID + (gq << 3);

    for (int k0 = 0; k0 < HID; k0 += 32) {
        // A fragments: row = rt*16 + lc, k = k0 + gq*8
        s16x8 ah[4], al[4];
        #pragma unroll
        for (int rt = 0; rt < 4; ++rt) {
            const int arow = (rt << 4) | lc;
            int abyte = arow * 512 + ((k0 + (gq << 3)) << 1);
            abyte ^= (arow & 7) << 4;
            ah[rt] = *reinterpret_cast<const s16x8*>(
                         reinterpret_cast<const char*>(xsh) + abyte);
            al[rt] = *reinterpret_cast<const s16x8*>(
                         reinterpret_cast<const char*>(xsl) + abyte);
        }
        #pragma unroll
        for (int ct = 0; ct < 8; ++ct) {
            const size_t boff = bbase + (size_t)ct * (16 * HID) + k0;
            const s16x8 bh = *reinterpret_cast<const s16x8*>(w1h + boff);
            const s16x8 bl = *reinterpret_cast<const s16x8*>(w1l + boff);
            #pragma unroll
            for (int rt = 0; rt < 4; ++rt) {
                acc[rt][ct] = __builtin_amdgcn_mfma_f32_16x16x32_bf16(ah[rt], bh, acc[rt][ct], 0, 0, 0);
                acc[rt][ct] = __builtin_amdgcn_mfma_f32_16x16x32_bf16(al[rt], bh, acc[rt][ct], 0, 0, 0);
                acc[rt][ct] = __builtin_amdgcn_mfma_f32_16x16x32_bf16(ah[rt], bl, acc[rt][ct], 0, 0, 0);
            }
        }
    }

    // ---- epilogue ----
    // C-layout per (rt,ct) tile: lane holds col wcol0+ct*16+lc, row rt*16+gq*4+reg.
    // 1) +b1 and per-row S1/S2 partials over this wave's 128 cols
    #pragma unroll
    for (int rt = 0; rt < 4; ++rt) {
        float s1[4] = {0.f, 0.f, 0.f, 0.f};
        float s2[4] = {0.f, 0.f, 0.f, 0.f};
        #pragma unroll
        for (int ct = 0; ct < 8; ++ct) {
            const float bb = prm[wcol0 + (ct << 4) + lc];
            #pragma unroll
            for (int reg = 0; reg < 4; ++reg) {
                const float v = acc[rt][ct][reg] + bb;
                acc[rt][ct][reg] = v;
                s1[reg] += v;
                s2[reg] = fmaf(v, v, s2[reg]);
            }
        }
        #pragma unroll
        for (int reg = 0; reg < 4; ++reg) {
            float a = s1[reg], q = s2[reg];
            a += __shfl_xor(a, 1); q += __shfl_xor(q, 1);
            a += __shfl_xor(a, 2); q += __shfl_xor(q, 2);
            a += __shfl_xor(a, 4); q += __shfl_xor(q, 4);
            a += __shfl_xor(a, 8); q += __shfl_xor(q, 8);
            if (lc == 0) {
                const int row = (rt << 4) + (gq << 2) + reg;
                redS1[w][row] = a;
                redS2[w][row] = q;
            }
        }
    }
    __syncthreads();

    // 2) 64 threads: mu, rstd per row
    if (tid < 64) {
        const float S1 = redS1[0][tid] + redS1[1][tid] + redS1[2][tid] + redS1[3][tid];
        const float S2 = redS2[0][tid] + redS2[1][tid] + redS2[2][tid] + redS2[3][tid];
        const float mu = S1 * (1.0f / HID2);
        const float var = S2 * (1.0f / HID2) - mu * mu;
        muv[tid] = mu;
        rsv[tid] = rsqrtf(var + LN_EPS);
    }
    __syncthreads();

    // 3) per-wave ReLU(LN)*W2 partials
    #pragma unroll
    for (int rt = 0; rt < 4; ++rt) {
        float tpart[4] = {0.f, 0.f, 0.f, 0.f};
        float mus[4], rss[4];
        #pragma unroll
        for (int reg = 0; reg < 4; ++reg) {
            const int row = (rt << 4) + (gq << 2) + reg;
            mus[reg] = muv[row];
            rss[reg] = rsv[row];
        }
        #pragma unroll
        for (int ct = 0; ct < 8; ++ct) {
            const int c = wcol0 + (ct << 4) + lc;
            const float lg = prm[512 + c], lb = prm[1024 + c], w2 = prm[1536 + c];
            #pragma unroll
            for (int reg = 0; reg < 4; ++reg) {
                float zn = (acc[rt][ct][reg] - mus[reg]) * rss[reg] * lg + lb;
                zn = fmaxf(zn, 0.f);
                tpart[reg] = fmaf(zn, w2, tpart[reg]);
            }
        }
        #pragma unroll
        for (int reg = 0; reg < 4; ++reg) {
            float t = tpart[reg];
            t += __shfl_xor(t, 1); t += __shfl_xor(t, 2);
            t += __shfl_xor(t, 4); t += __shfl_xor(t, 8);
            if (lc == 0) redT[w][(rt << 4) + (gq << 2) + reg] = t;
        }
    }
    __syncthreads();

    // 4) final: sum wave partials, write logits
    if (tid < 64) {
        const float t = redT[0][tid] + redT[1][tid] + redT[2][tid] + redT[3][tid];
        logits[row0 + tid] = t + b2[0];
    }
}

// ---------------------------------------------------------------------------
// K2: per-graph softmax + seed selection (first-index max of node_prob).
// ---------------------------------------------------------------------------
__global__ __launch_bounds__(256)
void softmax_seed_kernel(const float* __restrict__ logits,
                         float* __restrict__ out_prob,
                         unsigned char* __restrict__ nm)
{
    const int gid  = blockIdx.x;
    const int tid  = threadIdx.x;
    const int node = gid * NPG + tid;
    const bool act = tid < NPG;

    __shared__ float redf[4];
    __shared__ int   redi[4];

    float l = act ? logits[node] : -INFINITY;

    float m = l;
    #pragma unroll
    for (int off = 32; off >= 1; off >>= 1) m = fmaxf(m, __shfl_xor(m, off));
    if ((tid & 63) == 0) redf[tid >> 6] = m;
    __syncthreads();
    const float bm = fmaxf(fmaxf(redf[0], redf[1]), fmaxf(redf[2], redf[3]));
    __syncthreads();

    const float e = act ? expf(l - bm) : 0.0f;
    float s = e;
    #pragma unroll
    for (int off = 32; off >= 1; off >>= 1) s += __shfl_xor(s, off);
    if ((tid & 63) == 0) redf[tid >> 6] = s;
    __syncthreads();
    const float bs = redf[0] + redf[1] + redf[2] + redf[3];
    __syncthreads();

    const float p = act ? e / bs : -1.0f;
    if (act) out_prob[node] = p;

    float pm = p;
    #pragma unroll
    for (int off = 32; off >= 1; off >>= 1) pm = fmaxf(pm, __shfl_xor(pm, off));
    if ((tid & 63) == 0) redf[tid >> 6] = pm;
    __syncthreads();
    const float bpm = fmaxf(fmaxf(redf[0], redf[1]), fmaxf(redf[2], redf[3]));

    int c = (act && p >= bpm) ? node : 0x7FFFFFFF;
    #pragma unroll
    for (int off = 32; off >= 1; off >>= 1) c = min(c, __shfl_xor(c, off));
    if ((tid & 63) == 0) redi[tid >> 6] = c;
    __syncthreads();
    if (tid == 0) {
        const int seed = min(min(redi[0], redi[1]), min(redi[2], redi[3]));
        nm[seed] = 1;   // level 1
    }
}

// ---------------------------------------------------------------------------
// K3/K4: one synchronous BFS hop (expand target -> source), level-tagged.
// ---------------------------------------------------------------------------
__global__ __launch_bounds__(256)
void bfs_pass_kernel(const int* __restrict__ ei, unsigned char* __restrict__ nm,
                     const int E, const int maxlvl, const int newlvl)
{
    const int stride = gridDim.x * blockDim.x;
    for (int e = blockIdx.x * blockDim.x + threadIdx.x; e < E; e += stride) {
        const int d  = ei[E + e];
        const int lv = nm[d];
        if (lv >= 1 && lv <= maxlvl) {
            const int s = ei[e];
            if (nm[s] == 0) nm[s] = (unsigned char)newlvl;
        }
    }
}

// ---------------------------------------------------------------------------
// K5: edge outputs + node-mask scatter (float32 outputs)
// ---------------------------------------------------------------------------
__global__ __launch_bounds__(256)
void edge_out_kernel(const int* __restrict__ ei, const float* __restrict__ logits,
                     const unsigned char* __restrict__ nm,
                     float* __restrict__ out_ew,
                     float* __restrict__ out_em,
                     unsigned char* __restrict__ nodemask, const int E)
{
    const int stride = gridDim.x * blockDim.x;
    for (int e = blockIdx.x * blockDim.x + threadIdx.x; e < E; e += stride) {
        const int s = ei[e];
        const int d = ei[E + e];
        const float lw = logits[s] + logits[d];
        const bool em  = (nm[s] != 0) && (nm[d] != 0);
        out_ew[e] = lw;
        out_em[e] = em ? 1.0f : 0.0f;
        if (em) { nodemask[s] = 1; nodemask[d] = 1; }
    }
}

// ---------------------------------------------------------------------------
// K6: node_mask -> float32 output
// ---------------------------------------------------------------------------
__global__ __launch_bounds__(256)
void node_mask_kernel(const unsigned char* __restrict__ nodemask,
                      float* __restrict__ out_nm, const int N)
{
    const int stride = gridDim.x * blockDim.x;
    for (int i = blockIdx.x * blockDim.x + threadIdx.x; i < N; i += stride)
        out_nm[i] = nodemask[i] ? 1.0f : 0.0f;
}

// ---------------------------------------------------------------------------
// K0: zero nm + nodemask scratch
// ---------------------------------------------------------------------------
__global__ __launch_bounds__(256)
void zero_ws_kernel(uint4* __restrict__ p, const int n16)
{
    const int i = blockIdx.x * blockDim.x + threadIdx.x;
    if (i < n16) p[i] = make_uint4(0u, 0u, 0u, 0u);
}

extern "C" void kernel_launch(void* const* d_in, const int* in_sizes, int n_in,
                              void* d_out, int out_size, void* d_ws, size_t ws_size,
                              hipStream_t stream)
{
    const float* h     = (const float*)d_in[0];
    const float* g     = (const float*)d_in[1];
    const int*   batch = (const int*)d_in[2];
    const int*   ei    = (const int*)d_in[3];
    const float* W1    = (const float*)d_in[4];
    const float* b1    = (const float*)d_in[5];
    const float* lng   = (const float*)d_in[6];
    const float* lnb   = (const float*)d_in[7];
    const float* W2    = (const float*)d_in[8];
    const float* b2    = (const float*)d_in[9];

    const int N = in_sizes[2];
    const int E = in_sizes[3] / 2;

    float* out        = (float*)d_out;
    float* out_prob   = out;                                  // [N]
    float* out_ew     = out + N;                              // [E]
    float* out_em     = out + (size_t)N + E;                  // [E]
    float* out_nmask  = out + (size_t)N + 2 * (size_t)E;      // [N]

    // workspace layout
    char* ws = (char*)d_ws;
    float*         logits   = (float*)ws;                               // N*4
    ushort_t*      w1h      = (ushort_t*)(ws + (size_t)N * 4);          // 512*256*2
    ushort_t*      w1l      = (ushort_t*)(ws + (size_t)N * 4 + 262144);
    unsigned char* nm       = (unsigned char*)(ws + (size_t)N * 4 + 524288);
    unsigned char* nodemask = nm + N;

    // zero nm + nodemask (2N bytes, 16B aligned)
    const int n16 = (2 * N) / 16;
    zero_ws_kernel<<<(n16 + 255) / 256, 256, 0, stream>>>((uint4*)nm, n16);

    w1_prep_kernel<<<HID2, HID, 0, stream>>>(W1, w1h, w1l);

    mlp_logits_mfma<<<N / 64, 256, 0, stream>>>(h, g, batch, w1h, w1l,
                                                b1, lng, lnb, W2, b2, logits);
    softmax_seed_kernel<<<N / NPG, 256, 0, stream>>>(logits, out_prob, nm);
    bfs_pass_kernel<<<4096, 256, 0, stream>>>(ei, nm, E, 1, 2);
    bfs_pass_kernel<<<4096, 256, 0, stream>>>(ei, nm, E, 2, 3);
    edge_out_kernel<<<4096, 256, 0, stream>>>(ei, logits, nm, out_ew, out_em,
                                              nodemask, E);
    node_mask_kernel<<<512, 256, 0, stream>>>(nodemask, out_nmask, N);
}

// Round 5
// 251.280 us; speedup vs baseline: 3.4307x; 1.3202x over previous
//
#include <hip/hip_runtime.h>
#include <hip/hip_bf16.h>

#define HID 256
#define HID2 512
#define NPG 200
#define LN_EPS 1e-5f

typedef float f32x4 __attribute__((ext_vector_type(4)));
typedef short s16x8 __attribute__((ext_vector_type(8)));
typedef unsigned short ushort_t;

// round-to-nearest-even float -> bf16 bit pattern
__device__ __forceinline__ ushort_t f2bf_rne(float x) {
    union { float f; unsigned int u; } c; c.f = x;
    unsigned int u = c.u;
    return (ushort_t)((u + 0x7fffu + ((u >> 16) & 1u)) >> 16);
}
__device__ __forceinline__ float bf2f(ushort_t h) {
    union { unsigned int u; float f; } c; c.u = ((unsigned int)h) << 16;
    return c.f;
}

// ---------------------------------------------------------------------------
// K_w1: transpose + bf16-split W1[256][512] -> W1T_hi/lo[512][256] (K-contiguous)
// ---------------------------------------------------------------------------
__global__ __launch_bounds__(256)
void w1_prep_kernel(const float* __restrict__ W1,
                    ushort_t* __restrict__ w1h, ushort_t* __restrict__ w1l)
{
    const int c = blockIdx.x;      // W1 column = W1T row, 0..511
    const int k = threadIdx.x;     // 0..255
    const float v = W1[(size_t)k * HID2 + c];
    const ushort_t hi = f2bf_rne(v);
    const float resid = v - bf2f(hi);
    const ushort_t lo = f2bf_rne(resid);
    w1h[(size_t)c * HID + k] = hi;
    w1l[(size_t)c * HID + k] = lo;
}

// ---------------------------------------------------------------------------
// K1: fused  x = h + g[batch];  z = x@W1 + b1;  LayerNorm; ReLU; logit = z.W2+b2
// bf16x3 MFMA. Block: 512 thr = 8 waves, BM=64 rows.
// Wave w owns cols w*64..+63 (4 col-tiles) x all 64 rows (4 row-tiles)
// -> acc = 16 f32x4 = 64 VGPRs; launch_bounds(512,4) caps VGPR at 128
// -> 4 waves/SIMD resident (2 blocks/CU by LDS), 2x round-4 occupancy.
// B-frags from global (L2-resident, loop-invariant lane base), A from
// swizzled LDS. Cross-wave LN/W2 reduction via LDS.
// ---------------------------------------------------------------------------
__global__ __launch_bounds__(512, 4)
void mlp_logits_mfma(const float* __restrict__ h, const float* __restrict__ g,
                     const int* __restrict__ batch,
                     const ushort_t* __restrict__ w1h, const ushort_t* __restrict__ w1l,
                     const float* __restrict__ b1,
                     const float* __restrict__ lng, const float* __restrict__ lnb,
                     const float* __restrict__ W2, const float* __restrict__ b2,
                     float* __restrict__ logits)
{
    __shared__ ushort_t xsh[64 * 256];   // 32 KB, swizzled
    __shared__ ushort_t xsl[64 * 256];   // 32 KB, swizzled
    __shared__ float prm[4 * 512];       // b1 | lng | lnb | W2
    __shared__ float redS1[8][64];
    __shared__ float redS2[8][64];
    __shared__ float redT[8][64];
    __shared__ float muv[64], rsv[64];

    const int tid  = threadIdx.x;
    const int row0 = blockIdx.x * 64;

    // ---- params -> LDS ----
    {
        const int c = tid;               // 0..511
        prm[c]        = b1[c];
        prm[512 + c]  = lng[c];
        prm[1024 + c] = lnb[c];
        prm[1536 + c] = W2[c];
    }

    // ---- stage x = h + g[batch], split to bf16 hi/lo in swizzled LDS ----
    #pragma unroll
    for (int i = 0; i < 4; ++i) {
        const int ci = tid + (i << 9);      // 0..2047
        const int r  = ci >> 5;             // 0..63
        const int kc = (ci & 31) << 3;      // 0..248
        const int grow = row0 + r;
        const int gb   = batch[grow];
        const float4* hp = reinterpret_cast<const float4*>(h + (size_t)grow * HID + kc);
        const float4* gp = reinterpret_cast<const float4*>(g + (size_t)gb   * HID + kc);
        const float4 h0 = hp[0], h1 = hp[1];
        const float4 g0 = gp[0], g1 = gp[1];
        float xv[8] = { h0.x + g0.x, h0.y + g0.y, h0.z + g0.z, h0.w + g0.w,
                        h1.x + g1.x, h1.y + g1.y, h1.z + g1.z, h1.w + g1.w };
        ushort_t hh[8], ll[8];
        #pragma unroll
        for (int j = 0; j < 8; ++j) {
            const ushort_t hi = f2bf_rne(xv[j]);
            hh[j] = hi;
            ll[j] = f2bf_rne(xv[j] - bf2f(hi));
        }
        int byte_off = r * 512 + (kc << 1);
        byte_off ^= (r & 7) << 4;
        *reinterpret_cast<s16x8*>(reinterpret_cast<char*>(xsh) + byte_off) =
            *reinterpret_cast<const s16x8*>(hh);
        *reinterpret_cast<s16x8*>(reinterpret_cast<char*>(xsl) + byte_off) =
            *reinterpret_cast<const s16x8*>(ll);
    }
    __syncthreads();

    const int w  = tid >> 6;       // wave 0..7 -> cols w*64..+63
    const int l  = tid & 63;
    const int lc = l & 15;         // A-row / B-col / C-col index within tile
    const int gq = l >> 4;         // k-chunk group 0..3 (and C row group)
    const int wcol0 = w << 6;

    f32x4 acc[4][4];               // [rt][ct]
    #pragma unroll
    for (int rt = 0; rt < 4; ++rt)
        #pragma unroll
        for (int ct = 0; ct < 4; ++ct) acc[rt][ct] = (f32x4){0.f, 0.f, 0.f, 0.f};

    // loop-invariant B lane base: col = wcol0 + ct*16 + lc, k base = gq*8
    const size_t bbase = (size_t)(wcol0 + lc) * HID + (gq << 3);

    for (int k0 = 0; k0 < HID; k0 += 32) {
        // B fragments first (global, L2) so loads issue before dependent MFMAs
        s16x8 bh[4], bl[4];
        #pragma unroll
        for (int ct = 0; ct < 4; ++ct) {
            const size_t boff = bbase + (size_t)ct * (16 * HID) + k0;
            bh[ct] = *reinterpret_cast<const s16x8*>(w1h + boff);
            bl[ct] = *reinterpret_cast<const s16x8*>(w1l + boff);
        }
        // A fragments: row = rt*16 + lc, k = k0 + gq*8
        s16x8 ah[4], al[4];
        #pragma unroll
        for (int rt = 0; rt < 4; ++rt) {
            const int arow = (rt << 4) | lc;
            int abyte = arow * 512 + ((k0 + (gq << 3)) << 1);
            abyte ^= (arow & 7) << 4;
            ah[rt] = *reinterpret_cast<const s16x8*>(
                         reinterpret_cast<const char*>(xsh) + abyte);
            al[rt] = *reinterpret_cast<const s16x8*>(
                         reinterpret_cast<const char*>(xsl) + abyte);
        }
        #pragma unroll
        for (int ct = 0; ct < 4; ++ct) {
            #pragma unroll
            for (int rt = 0; rt < 4; ++rt) {
                acc[rt][ct] = __builtin_amdgcn_mfma_f32_16x16x32_bf16(ah[rt], bh[ct], acc[rt][ct], 0, 0, 0);
                acc[rt][ct] = __builtin_amdgcn_mfma_f32_16x16x32_bf16(al[rt], bh[ct], acc[rt][ct], 0, 0, 0);
                acc[rt][ct] = __builtin_amdgcn_mfma_f32_16x16x32_bf16(ah[rt], bl[ct], acc[rt][ct], 0, 0, 0);
            }
        }
    }

    // ---- epilogue ----
    // C-layout per (rt,ct) tile: lane holds col wcol0+ct*16+lc, row rt*16+gq*4+reg.
    // 1) +b1 and per-row S1/S2 partials over this wave's 64 cols
    #pragma unroll
    for (int rt = 0; rt < 4; ++rt) {
        float s1[4] = {0.f, 0.f, 0.f, 0.f};
        float s2[4] = {0.f, 0.f, 0.f, 0.f};
        #pragma unroll
        for (int ct = 0; ct < 4; ++ct) {
            const float bb = prm[wcol0 + (ct << 4) + lc];
            #pragma unroll
            for (int reg = 0; reg < 4; ++reg) {
                const float v = acc[rt][ct][reg] + bb;
                acc[rt][ct][reg] = v;
                s1[reg] += v;
                s2[reg] = fmaf(v, v, s2[reg]);
            }
        }
        #pragma unroll
        for (int reg = 0; reg < 4; ++reg) {
            float a = s1[reg], q = s2[reg];
            a += __shfl_xor(a, 1); q += __shfl_xor(q, 1);
            a += __shfl_xor(a, 2); q += __shfl_xor(q, 2);
            a += __shfl_xor(a, 4); q += __shfl_xor(q, 4);
            a += __shfl_xor(a, 8); q += __shfl_xor(q, 8);
            if (lc == 0) {
                const int row = (rt << 4) + (gq << 2) + reg;
                redS1[w][row] = a;
                redS2[w][row] = q;
            }
        }
    }
    __syncthreads();

    // 2) 64 threads: mu, rstd per row
    if (tid < 64) {
        float S1 = 0.f, S2 = 0.f;
        #pragma unroll
        for (int i = 0; i < 8; ++i) { S1 += redS1[i][tid]; S2 += redS2[i][tid]; }
        const float mu = S1 * (1.0f / HID2);
        const float var = S2 * (1.0f / HID2) - mu * mu;
        muv[tid] = mu;
        rsv[tid] = rsqrtf(var + LN_EPS);
    }
    __syncthreads();

    // 3) per-wave ReLU(LN)*W2 partials
    #pragma unroll
    for (int rt = 0; rt < 4; ++rt) {
        float tpart[4] = {0.f, 0.f, 0.f, 0.f};
        float mus[4], rss[4];
        #pragma unroll
        for (int reg = 0; reg < 4; ++reg) {
            const int row = (rt << 4) + (gq << 2) + reg;
            mus[reg] = muv[row];
            rss[reg] = rsv[row];
        }
        #pragma unroll
        for (int ct = 0; ct < 4; ++ct) {
            const int c = wcol0 + (ct << 4) + lc;
            const float lg = prm[512 + c], lb = prm[1024 + c], w2 = prm[1536 + c];
            #pragma unroll
            for (int reg = 0; reg < 4; ++reg) {
                float zn = (acc[rt][ct][reg] - mus[reg]) * rss[reg] * lg + lb;
                zn = fmaxf(zn, 0.f);
                tpart[reg] = fmaf(zn, w2, tpart[reg]);
            }
        }
        #pragma unroll
        for (int reg = 0; reg < 4; ++reg) {
            float t = tpart[reg];
            t += __shfl_xor(t, 1); t += __shfl_xor(t, 2);
            t += __shfl_xor(t, 4); t += __shfl_xor(t, 8);
            if (lc == 0) redT[w][(rt << 4) + (gq << 2) + reg] = t;
        }
    }
    __syncthreads();

    // 4) final: sum wave partials, write logits
    if (tid < 64) {
        float t = 0.f;
        #pragma unroll
        for (int i = 0; i < 8; ++i) t += redT[i][tid];
        logits[row0 + tid] = t + b2[0];
    }
}

// ---------------------------------------------------------------------------
// K2: per-graph softmax + seed selection (first-index max of node_prob).
// ---------------------------------------------------------------------------
__global__ __launch_bounds__(256)
void softmax_seed_kernel(const float* __restrict__ logits,
                         float* __restrict__ out_prob,
                         unsigned char* __restrict__ nm)
{
    const int gid  = blockIdx.x;
    const int tid  = threadIdx.x;
    const int node = gid * NPG + tid;
    const bool act = tid < NPG;

    __shared__ float redf[4];
    __shared__ int   redi[4];

    float l = act ? logits[node] : -INFINITY;

    float m = l;
    #pragma unroll
    for (int off = 32; off >= 1; off >>= 1) m = fmaxf(m, __shfl_xor(m, off));
    if ((tid & 63) == 0) redf[tid >> 6] = m;
    __syncthreads();
    const float bm = fmaxf(fmaxf(redf[0], redf[1]), fmaxf(redf[2], redf[3]));
    __syncthreads();

    const float e = act ? expf(l - bm) : 0.0f;
    float s = e;
    #pragma unroll
    for (int off = 32; off >= 1; off >>= 1) s += __shfl_xor(s, off);
    if ((tid & 63) == 0) redf[tid >> 6] = s;
    __syncthreads();
    const float bs = redf[0] + redf[1] + redf[2] + redf[3];
    __syncthreads();

    const float p = act ? e / bs : -1.0f;
    if (act) out_prob[node] = p;

    float pm = p;
    #pragma unroll
    for (int off = 32; off >= 1; off >>= 1) pm = fmaxf(pm, __shfl_xor(pm, off));
    if ((tid & 63) == 0) redf[tid >> 6] = pm;
    __syncthreads();
    const float bpm = fmaxf(fmaxf(redf[0], redf[1]), fmaxf(redf[2], redf[3]));

    int c = (act && p >= bpm) ? node : 0x7FFFFFFF;
    #pragma unroll
    for (int off = 32; off >= 1; off >>= 1) c = min(c, __shfl_xor(c, off));
    if ((tid & 63) == 0) redi[tid >> 6] = c;
    __syncthreads();
    if (tid == 0) {
        const int seed = min(min(redi[0], redi[1]), min(redi[2], redi[3]));
        nm[seed] = 1;   // level 1
    }
}

// ---------------------------------------------------------------------------
// K3/K4: one synchronous BFS hop (expand target -> source), level-tagged.
// ---------------------------------------------------------------------------
__global__ __launch_bounds__(256)
void bfs_pass_kernel(const int* __restrict__ ei, unsigned char* __restrict__ nm,
                     const int E, const int maxlvl, const int newlvl)
{
    const int stride = gridDim.x * blockDim.x;
    for (int e = blockIdx.x * blockDim.x + threadIdx.x; e < E; e += stride) {
        const int d  = ei[E + e];
        const int lv = nm[d];
        if (lv >= 1 && lv <= maxlvl) {
            const int s = ei[e];
            if (nm[s] == 0) nm[s] = (unsigned char)newlvl;
        }
    }
}

// ---------------------------------------------------------------------------
// K5: edge outputs + node-mask scatter (float32 outputs)
// ---------------------------------------------------------------------------
__global__ __launch_bounds__(256)
void edge_out_kernel(const int* __restrict__ ei, const float* __restrict__ logits,
                     const unsigned char* __restrict__ nm,
                     float* __restrict__ out_ew,
                     float* __restrict__ out_em,
                     unsigned char* __restrict__ nodemask, const int E)
{
    const int stride = gridDim.x * blockDim.x;
    for (int e = blockIdx.x * blockDim.x + threadIdx.x; e < E; e += stride) {
        const int s = ei[e];
        const int d = ei[E + e];
        const float lw = logits[s] + logits[d];
        const bool em  = (nm[s] != 0) && (nm[d] != 0);
        out_ew[e] = lw;
        out_em[e] = em ? 1.0f : 0.0f;
        if (em) { nodemask[s] = 1; nodemask[d] = 1; }
    }
}

// ---------------------------------------------------------------------------
// K6: node_mask -> float32 output
// ---------------------------------------------------------------------------
__global__ __launch_bounds__(256)
void node_mask_kernel(const unsigned char* __restrict__ nodemask,
                      float* __restrict__ out_nm, const int N)
{
    const int stride = gridDim.x * blockDim.x;
    for (int i = blockIdx.x * blockDim.x + threadIdx.x; i < N; i += stride)
        out_nm[i] = nodemask[i] ? 1.0f : 0.0f;
}

// ---------------------------------------------------------------------------
// K0: zero nm + nodemask scratch
// ---------------------------------------------------------------------------
__global__ __launch_bounds__(256)
void zero_ws_kernel(uint4* __restrict__ p, const int n16)
{
    const int i = blockIdx.x * blockDim.x + threadIdx.x;
    if (i < n16) p[i] = make_uint4(0u, 0u, 0u, 0u);
}

extern "C" void kernel_launch(void* const* d_in, const int* in_sizes, int n_in,
                              void* d_out, int out_size, void* d_ws, size_t ws_size,
                              hipStream_t stream)
{
    const float* h     = (const float*)d_in[0];
    const float* g     = (const float*)d_in[1];
    const int*   batch = (const int*)d_in[2];
    const int*   ei    = (const int*)d_in[3];
    const float* W1    = (const float*)d_in[4];
    const float* b1    = (const float*)d_in[5];
    const float* lng   = (const float*)d_in[6];
    const float* lnb   = (const float*)d_in[7];
    const float* W2    = (const float*)d_in[8];
    const float* b2    = (const float*)d_in[9];

    const int N = in_sizes[2];
    const int E = in_sizes[3] / 2;

    float* out        = (float*)d_out;
    float* out_prob   = out;                                  // [N]
    float* out_ew     = out + N;                              // [E]
    float* out_em     = out + (size_t)N + E;                  // [E]
    float* out_nmask  = out + (size_t)N + 2 * (size_t)E;      // [N]

    // workspace layout
    char* ws = (char*)d_ws;
    float*         logits   = (float*)ws;                               // N*4
    ushort_t*      w1h      = (ushort_t*)(ws + (size_t)N * 4);          // 512*256*2
    ushort_t*      w1l      = (ushort_t*)(ws + (size_t)N * 4 + 262144);
    unsigned char* nm       = (unsigned char*)(ws + (size_t)N * 4 + 524288);
    unsigned char* nodemask = nm + N;

    // zero nm + nodemask (2N bytes, 16B aligned)
    const int n16 = (2 * N) / 16;
    zero_ws_kernel<<<(n16 + 255) / 256, 256, 0, stream>>>((uint4*)nm, n16);

    w1_prep_kernel<<<HID2, HID, 0, stream>>>(W1, w1h, w1l);

    mlp_logits_mfma<<<N / 64, 512, 0, stream>>>(h, g, batch, w1h, w1l,
                                                b1, lng, lnb, W2, b2, logits);
    softmax_seed_kernel<<<N / NPG, 256, 0, stream>>>(logits, out_prob, nm);
    bfs_pass_kernel<<<4096, 256, 0, stream>>>(ei, nm, E, 1, 2);
    bfs_pass_kernel<<<4096, 256, 0, stream>>>(ei, nm, E, 2, 3);
    edge_out_kernel<<<4096, 256, 0, stream>>>(ei, logits, nm, out_ew, out_em,
                                              nodemask, E);
    node_mask_kernel<<<512, 256, 0, stream>>>(nodemask, out_nmask, N);
}

// Round 6
// 233.113 us; speedup vs baseline: 3.6980x; 1.0779x over previous
//
#include <hip/hip_runtime.h>
#include <hip/hip_bf16.h>

#define HID 256
#define HID2 512
#define NPG 200
#define LN_EPS 1e-5f

typedef float f32x4 __attribute__((ext_vector_type(4)));
typedef short s16x8 __attribute__((ext_vector_type(8)));
typedef unsigned short ushort_t;

// round-to-nearest-even float -> bf16 bit pattern
__device__ __forceinline__ ushort_t f2bf_rne(float x) {
    union { float f; unsigned int u; } c; c.f = x;
    unsigned int u = c.u;
    return (ushort_t)((u + 0x7fffu + ((u >> 16) & 1u)) >> 16);
}
__device__ __forceinline__ float bf2f(ushort_t h) {
    union { unsigned int u; float f; } c; c.u = ((unsigned int)h) << 16;
    return c.f;
}

// ---------------------------------------------------------------------------
// K_w1: W1[256][512] -> fragment-major bf16 hi/lo buffers.
// Layout: w1f[(((tile*8 + kq)*64) + lane)*8 + j], lane = gq*16+lc,
// holding W1[k][col] with col = tile*16+lc, k = kq*32+gq*8+j.
// A wave's B-load for (tile,kq) is then base + l*16B -> fully coalesced 1KB.
// ---------------------------------------------------------------------------
__global__ __launch_bounds__(256)
void w1_prep_kernel(const float* __restrict__ W1,
                    ushort_t* __restrict__ w1h, ushort_t* __restrict__ w1l)
{
    const int col = blockIdx.x;    // 0..511
    const int k   = threadIdx.x;   // 0..255
    const float v = W1[(size_t)k * HID2 + col];
    const ushort_t hi = f2bf_rne(v);
    const ushort_t lo = f2bf_rne(v - bf2f(hi));
    const int tile = col >> 4, lc = col & 15;
    const int kq = k >> 5, gq = (k >> 3) & 3, j = k & 7;
    const size_t idx = ((((size_t)tile << 3) + kq) * 64 + (gq << 4) + lc) * 8 + j;
    w1h[idx] = hi;
    w1l[idx] = lo;
}

// ---------------------------------------------------------------------------
// K1: fused  x = h + g[batch];  z = x@W1 + b1;  LayerNorm; ReLU; logit = z.W2+b2
// bf16x3 MFMA. Block: 512 thr = 8 waves, BM=64 rows.
// Wave w owns cols w*64..+63 (4 col-tiles = tiles w*4..w*4+3) x 64 rows.
// B-frags: fragment-major global buffer, coalesced 1KB wave loads (L1/L2-hot).
// A-frags: swizzled LDS. MFMA order term-outer (no same-acc back-to-back).
// ---------------------------------------------------------------------------
__global__ __launch_bounds__(512, 4)
void mlp_logits_mfma(const float* __restrict__ h, const float* __restrict__ g,
                     const int* __restrict__ batch,
                     const ushort_t* __restrict__ w1h, const ushort_t* __restrict__ w1l,
                     const float* __restrict__ b1,
                     const float* __restrict__ lng, const float* __restrict__ lnb,
                     const float* __restrict__ W2, const float* __restrict__ b2,
                     float* __restrict__ logits)
{
    __shared__ ushort_t xsh[64 * 256];   // 32 KB, swizzled
    __shared__ ushort_t xsl[64 * 256];   // 32 KB, swizzled
    __shared__ float prm[4 * 512];       // b1 | lng | lnb | W2
    __shared__ float redS1[8][64];
    __shared__ float redS2[8][64];
    __shared__ float redT[8][64];
    __shared__ float muv[64], rsv[64];

    const int tid  = threadIdx.x;
    const int row0 = blockIdx.x * 64;

    // ---- params -> LDS ----
    {
        const int c = tid;               // 0..511
        prm[c]        = b1[c];
        prm[512 + c]  = lng[c];
        prm[1024 + c] = lnb[c];
        prm[1536 + c] = W2[c];
    }

    // ---- stage x = h + g[batch], split to bf16 hi/lo in swizzled LDS ----
    #pragma unroll
    for (int i = 0; i < 4; ++i) {
        const int ci = tid + (i << 9);      // 0..2047
        const int r  = ci >> 5;             // 0..63
        const int kc = (ci & 31) << 3;      // 0..248
        const int grow = row0 + r;
        const int gb   = batch[grow];
        const float4* hp = reinterpret_cast<const float4*>(h + (size_t)grow * HID + kc);
        const float4* gp = reinterpret_cast<const float4*>(g + (size_t)gb   * HID + kc);
        const float4 h0 = hp[0], h1 = hp[1];
        const float4 g0 = gp[0], g1 = gp[1];
        float xv[8] = { h0.x + g0.x, h0.y + g0.y, h0.z + g0.z, h0.w + g0.w,
                        h1.x + g1.x, h1.y + g1.y, h1.z + g1.z, h1.w + g1.w };
        ushort_t hh[8], ll[8];
        #pragma unroll
        for (int j = 0; j < 8; ++j) {
            const ushort_t hi = f2bf_rne(xv[j]);
            hh[j] = hi;
            ll[j] = f2bf_rne(xv[j] - bf2f(hi));
        }
        int byte_off = r * 512 + (kc << 1);
        byte_off ^= (r & 7) << 4;
        *reinterpret_cast<s16x8*>(reinterpret_cast<char*>(xsh) + byte_off) =
            *reinterpret_cast<const s16x8*>(hh);
        *reinterpret_cast<s16x8*>(reinterpret_cast<char*>(xsl) + byte_off) =
            *reinterpret_cast<const s16x8*>(ll);
    }
    __syncthreads();

    const int w  = tid >> 6;       // wave 0..7 -> cols w*64..+63
    const int l  = tid & 63;
    const int lc = l & 15;         // A-row / B-col / C-col index within tile
    const int gq = l >> 4;         // k-chunk group 0..3 (and C row group)
    const int wcol0 = w << 6;

    f32x4 acc[4][4];               // [rt][ct]
    #pragma unroll
    for (int rt = 0; rt < 4; ++rt)
        #pragma unroll
        for (int ct = 0; ct < 4; ++ct) acc[rt][ct] = (f32x4){0.f, 0.f, 0.f, 0.f};

    // fragment-major B base for this wave+lane: tiles w*4..w*4+3
    const ushort_t* bfh = w1h + (((size_t)w << 2) << 3) * 512 + (size_t)l * 8;
    const ushort_t* bfl = w1l + (((size_t)w << 2) << 3) * 512 + (size_t)l * 8;

    for (int kq = 0; kq < 8; ++kq) {
        // B fragments: coalesced 1KB wave loads, (ct*8+kq)*512 elements apart
        s16x8 bh[4], bl[4];
        #pragma unroll
        for (int ct = 0; ct < 4; ++ct) {
            const size_t foff = (size_t)((ct << 3) + kq) * 512;
            bh[ct] = *reinterpret_cast<const s16x8*>(bfh + foff);
            bl[ct] = *reinterpret_cast<const s16x8*>(bfl + foff);
        }
        // A fragments: row = rt*16 + lc, k = kq*32 + gq*8
        s16x8 ah[4], al[4];
        #pragma unroll
        for (int rt = 0; rt < 4; ++rt) {
            const int arow = (rt << 4) | lc;
            int abyte = arow * 512 + (((kq << 5) + (gq << 3)) << 1);
            abyte ^= (arow & 7) << 4;
            ah[rt] = *reinterpret_cast<const s16x8*>(
                         reinterpret_cast<const char*>(xsh) + abyte);
            al[rt] = *reinterpret_cast<const s16x8*>(
                         reinterpret_cast<const char*>(xsl) + abyte);
        }
        // term-outer MFMA order: 16 independent accs between same-acc reuse
        #pragma unroll
        for (int ct = 0; ct < 4; ++ct)
            #pragma unroll
            for (int rt = 0; rt < 4; ++rt)
                acc[rt][ct] = __builtin_amdgcn_mfma_f32_16x16x32_bf16(ah[rt], bh[ct], acc[rt][ct], 0, 0, 0);
        #pragma unroll
        for (int ct = 0; ct < 4; ++ct)
            #pragma unroll
            for (int rt = 0; rt < 4; ++rt)
                acc[rt][ct] = __builtin_amdgcn_mfma_f32_16x16x32_bf16(al[rt], bh[ct], acc[rt][ct], 0, 0, 0);
        #pragma unroll
        for (int ct = 0; ct < 4; ++ct)
            #pragma unroll
            for (int rt = 0; rt < 4; ++rt)
                acc[rt][ct] = __builtin_amdgcn_mfma_f32_16x16x32_bf16(ah[rt], bl[ct], acc[rt][ct], 0, 0, 0);
    }

    // ---- epilogue ----
    // C-layout per (rt,ct) tile: lane holds col wcol0+ct*16+lc, row rt*16+gq*4+reg.
    #pragma unroll
    for (int rt = 0; rt < 4; ++rt) {
        float s1[4] = {0.f, 0.f, 0.f, 0.f};
        float s2[4] = {0.f, 0.f, 0.f, 0.f};
        #pragma unroll
        for (int ct = 0; ct < 4; ++ct) {
            const float bb = prm[wcol0 + (ct << 4) + lc];
            #pragma unroll
            for (int reg = 0; reg < 4; ++reg) {
                const float v = acc[rt][ct][reg] + bb;
                acc[rt][ct][reg] = v;
                s1[reg] += v;
                s2[reg] = fmaf(v, v, s2[reg]);
            }
        }
        #pragma unroll
        for (int reg = 0; reg < 4; ++reg) {
            float a = s1[reg], q = s2[reg];
            a += __shfl_xor(a, 1); q += __shfl_xor(q, 1);
            a += __shfl_xor(a, 2); q += __shfl_xor(q, 2);
            a += __shfl_xor(a, 4); q += __shfl_xor(q, 4);
            a += __shfl_xor(a, 8); q += __shfl_xor(q, 8);
            if (lc == 0) {
                const int row = (rt << 4) + (gq << 2) + reg;
                redS1[w][row] = a;
                redS2[w][row] = q;
            }
        }
    }
    __syncthreads();

    if (tid < 64) {
        float S1 = 0.f, S2 = 0.f;
        #pragma unroll
        for (int i = 0; i < 8; ++i) { S1 += redS1[i][tid]; S2 += redS2[i][tid]; }
        const float mu = S1 * (1.0f / HID2);
        const float var = S2 * (1.0f / HID2) - mu * mu;
        muv[tid] = mu;
        rsv[tid] = rsqrtf(var + LN_EPS);
    }
    __syncthreads();

    #pragma unroll
    for (int rt = 0; rt < 4; ++rt) {
        float tpart[4] = {0.f, 0.f, 0.f, 0.f};
        float mus[4], rss[4];
        #pragma unroll
        for (int reg = 0; reg < 4; ++reg) {
            const int row = (rt << 4) + (gq << 2) + reg;
            mus[reg] = muv[row];
            rss[reg] = rsv[row];
        }
        #pragma unroll
        for (int ct = 0; ct < 4; ++ct) {
            const int c = wcol0 + (ct << 4) + lc;
            const float lg = prm[512 + c], lb = prm[1024 + c], w2 = prm[1536 + c];
            #pragma unroll
            for (int reg = 0; reg < 4; ++reg) {
                float zn = (acc[rt][ct][reg] - mus[reg]) * rss[reg] * lg + lb;
                zn = fmaxf(zn, 0.f);
                tpart[reg] = fmaf(zn, w2, tpart[reg]);
            }
        }
        #pragma unroll
        for (int reg = 0; reg < 4; ++reg) {
            float t = tpart[reg];
            t += __shfl_xor(t, 1); t += __shfl_xor(t, 2);
            t += __shfl_xor(t, 4); t += __shfl_xor(t, 8);
            if (lc == 0) redT[w][(rt << 4) + (gq << 2) + reg] = t;
        }
    }
    __syncthreads();

    if (tid < 64) {
        float t = 0.f;
        #pragma unroll
        for (int i = 0; i < 8; ++i) t += redT[i][tid];
        logits[row0 + tid] = t + b2[0];
    }
}

// ---------------------------------------------------------------------------
// K2: per-graph softmax + seed selection (first-index max of node_prob).
// ---------------------------------------------------------------------------
__global__ __launch_bounds__(256)
void softmax_seed_kernel(const float* __restrict__ logits,
                         float* __restrict__ out_prob,
                         unsigned char* __restrict__ nm)
{
    const int gid  = blockIdx.x;
    const int tid  = threadIdx.x;
    const int node = gid * NPG + tid;
    const bool act = tid < NPG;

    __shared__ float redf[4];
    __shared__ int   redi[4];

    float l = act ? logits[node] : -INFINITY;

    float m = l;
    #pragma unroll
    for (int off = 32; off >= 1; off >>= 1) m = fmaxf(m, __shfl_xor(m, off));
    if ((tid & 63) == 0) redf[tid >> 6] = m;
    __syncthreads();
    const float bm = fmaxf(fmaxf(redf[0], redf[1]), fmaxf(redf[2], redf[3]));
    __syncthreads();

    const float e = act ? expf(l - bm) : 0.0f;
    float s = e;
    #pragma unroll
    for (int off = 32; off >= 1; off >>= 1) s += __shfl_xor(s, off);
    if ((tid & 63) == 0) redf[tid >> 6] = s;
    __syncthreads();
    const float bs = redf[0] + redf[1] + redf[2] + redf[3];
    __syncthreads();

    const float p = act ? e / bs : -1.0f;
    if (act) out_prob[node] = p;

    float pm = p;
    #pragma unroll
    for (int off = 32; off >= 1; off >>= 1) pm = fmaxf(pm, __shfl_xor(pm, off));
    if ((tid & 63) == 0) redf[tid >> 6] = pm;
    __syncthreads();
    const float bpm = fmaxf(fmaxf(redf[0], redf[1]), fmaxf(redf[2], redf[3]));

    int c = (act && p >= bpm) ? node : 0x7FFFFFFF;
    #pragma unroll
    for (int off = 32; off >= 1; off >>= 1) c = min(c, __shfl_xor(c, off));
    if ((tid & 63) == 0) redi[tid >> 6] = c;
    __syncthreads();
    if (tid == 0) {
        const int seed = min(min(redi[0], redi[1]), min(redi[2], redi[3]));
        nm[seed] = 1;   // level 1
    }
}

// ---------------------------------------------------------------------------
// K3/K4: one synchronous BFS hop (expand target -> source), level-tagged.
// ---------------------------------------------------------------------------
__global__ __launch_bounds__(256)
void bfs_pass_kernel(const int* __restrict__ ei, unsigned char* __restrict__ nm,
                     const int E, const int maxlvl, const int newlvl)
{
    const int stride = gridDim.x * blockDim.x;
    for (int e = blockIdx.x * blockDim.x + threadIdx.x; e < E; e += stride) {
        const int d  = ei[E + e];
        const int lv = nm[d];
        if (lv >= 1 && lv <= maxlvl) {
            const int s = ei[e];
            if (nm[s] == 0) nm[s] = (unsigned char)newlvl;
        }
    }
}

// ---------------------------------------------------------------------------
// K5: edge outputs + node-mask scatter (float32 outputs)
// ---------------------------------------------------------------------------
__global__ __launch_bounds__(256)
void edge_out_kernel(const int* __restrict__ ei, const float* __restrict__ logits,
                     const unsigned char* __restrict__ nm,
                     float* __restrict__ out_ew,
                     float* __restrict__ out_em,
                     unsigned char* __restrict__ nodemask, const int E)
{
    const int stride = gridDim.x * blockDim.x;
    for (int e = blockIdx.x * blockDim.x + threadIdx.x; e < E; e += stride) {
        const int s = ei[e];
        const int d = ei[E + e];
        const float lw = logits[s] + logits[d];
        const bool em  = (nm[s] != 0) && (nm[d] != 0);
        out_ew[e] = lw;
        out_em[e] = em ? 1.0f : 0.0f;
        if (em) { nodemask[s] = 1; nodemask[d] = 1; }
    }
}

// ---------------------------------------------------------------------------
// K6: node_mask -> float32 output
// ---------------------------------------------------------------------------
__global__ __launch_bounds__(256)
void node_mask_kernel(const unsigned char* __restrict__ nodemask,
                      float* __restrict__ out_nm, const int N)
{
    const int stride = gridDim.x * blockDim.x;
    for (int i = blockIdx.x * blockDim.x + threadIdx.x; i < N; i += stride)
        out_nm[i] = nodemask[i] ? 1.0f : 0.0f;
}

// ---------------------------------------------------------------------------
// K0: zero nm + nodemask scratch
// ---------------------------------------------------------------------------
__global__ __launch_bounds__(256)
void zero_ws_kernel(uint4* __restrict__ p, const int n16)
{
    const int i = blockIdx.x * blockDim.x + threadIdx.x;
    if (i < n16) p[i] = make_uint4(0u, 0u, 0u, 0u);
}

extern "C" void kernel_launch(void* const* d_in, const int* in_sizes, int n_in,
                              void* d_out, int out_size, void* d_ws, size_t ws_size,
                              hipStream_t stream)
{
    const float* h     = (const float*)d_in[0];
    const float* g     = (const float*)d_in[1];
    const int*   batch = (const int*)d_in[2];
    const int*   ei    = (const int*)d_in[3];
    const float* W1    = (const float*)d_in[4];
    const float* b1    = (const float*)d_in[5];
    const float* lng   = (const float*)d_in[6];
    const float* lnb   = (const float*)d_in[7];
    const float* W2    = (const float*)d_in[8];
    const float* b2    = (const float*)d_in[9];

    const int N = in_sizes[2];
    const int E = in_sizes[3] / 2;

    float* out        = (float*)d_out;
    float* out_prob   = out;                                  // [N]
    float* out_ew     = out + N;                              // [E]
    float* out_em     = out + (size_t)N + E;                  // [E]
    float* out_nmask  = out + (size_t)N + 2 * (size_t)E;      // [N]

    // workspace layout
    char* ws = (char*)d_ws;
    float*         logits   = (float*)ws;                               // N*4
    ushort_t*      w1h      = (ushort_t*)(ws + (size_t)N * 4);          // 512*256*2
    ushort_t*      w1l      = (ushort_t*)(ws + (size_t)N * 4 + 262144);
    unsigned char* nm       = (unsigned char*)(ws + (size_t)N * 4 + 524288);
    unsigned char* nodemask = nm + N;

    // zero nm + nodemask (2N bytes, 16B aligned)
    const int n16 = (2 * N) / 16;
    zero_ws_kernel<<<(n16 + 255) / 256, 256, 0, stream>>>((uint4*)nm, n16);

    w1_prep_kernel<<<HID2, HID, 0, stream>>>(W1, w1h, w1l);

    mlp_logits_mfma<<<N / 64, 512, 0, stream>>>(h, g, batch, w1h, w1l,
                                                b1, lng, lnb, W2, b2, logits);
    softmax_seed_kernel<<<N / NPG, 256, 0, stream>>>(logits, out_prob, nm);
    bfs_pass_kernel<<<4096, 256, 0, stream>>>(ei, nm, E, 1, 2);
    bfs_pass_kernel<<<4096, 256, 0, stream>>>(ei, nm, E, 2, 3);
    edge_out_kernel<<<4096, 256, 0, stream>>>(ei, logits, nm, out_ew, out_em,
                                              nodemask, E);
    node_mask_kernel<<<512, 256, 0, stream>>>(nodemask, out_nmask, N);
}